// Round 1
// baseline (10247.922 us; speedup 1.0000x reference)
//
#include <hip/hip_runtime.h>

#define NUM_USERS 100000
#define NUM_ITEMS 50000
#define N_NODES   150000   // NUM_USERS + NUM_ITEMS
#define EMBED_DIM 64
#define NUM_EDGES 4000000

// float4 element counts
#define N_USER4  (NUM_USERS * EMBED_DIM / 4)   // 1,600,000
#define N_TOT4   (N_NODES  * EMBED_DIM / 4)    // 2,400,000

// ---------------------------------------------------------------------------
// init: cur = out = concat(user_emb, item_emb); next = 0
// ---------------------------------------------------------------------------
__global__ void init_kernel(const float4* __restrict__ ue,
                            const float4* __restrict__ ie,
                            float4* __restrict__ cur,
                            float4* __restrict__ nxt,
                            float4* __restrict__ out) {
    int i = blockIdx.x * blockDim.x + threadIdx.x;
    if (i >= N_TOT4) return;
    float4 v = (i < N_USER4) ? ue[i] : ie[i - N_USER4];
    cur[i] = v;
    out[i] = v;
    nxt[i] = make_float4(0.f, 0.f, 0.f, 0.f);
}

// ---------------------------------------------------------------------------
// edge scatter: y[row] += val * x[col]   (16 lanes per edge, float4 per lane)
// ---------------------------------------------------------------------------
__global__ void edge_kernel(const int*   __restrict__ row,
                            const int*   __restrict__ col,
                            const float* __restrict__ val,
                            const float* __restrict__ x,
                            float*       __restrict__ y) {
    long gid = (long)blockIdx.x * blockDim.x + threadIdx.x;
    int e = (int)(gid >> 4);
    if (e >= NUM_EDGES) return;
    int d = ((int)gid & 15) * 4;

    int   r = row[e];
    int   c = col[e];
    float v = val[e];

    const float4 xv = *(const float4*)(x + (long)c * EMBED_DIM + d);
    float* yp = y + (long)r * EMBED_DIM + d;
    atomicAdd(yp + 0, v * xv.x);
    atomicAdd(yp + 1, v * xv.y);
    atomicAdd(yp + 2, v * xv.z);
    atomicAdd(yp + 3, v * xv.w);
}

// ---------------------------------------------------------------------------
// update: out += nxt; zero the other ping-pong buffer for the next layer
// ---------------------------------------------------------------------------
__global__ void update_kernel(float4* __restrict__ out,
                              const float4* __restrict__ nxt,
                              float4* __restrict__ zero_buf) {
    int i = blockIdx.x * blockDim.x + threadIdx.x;
    if (i >= N_TOT4) return;
    float4 o = out[i];
    float4 n = nxt[i];
    o.x += n.x; o.y += n.y; o.z += n.z; o.w += n.w;
    out[i] = o;
    zero_buf[i] = make_float4(0.f, 0.f, 0.f, 0.f);
}

// ---------------------------------------------------------------------------
// final: out = (out + nxt) * 0.25
// ---------------------------------------------------------------------------
__global__ void final_kernel(float4* __restrict__ out,
                             const float4* __restrict__ nxt) {
    int i = blockIdx.x * blockDim.x + threadIdx.x;
    if (i >= N_TOT4) return;
    float4 o = out[i];
    float4 n = nxt[i];
    out[i] = make_float4((o.x + n.x) * 0.25f,
                         (o.y + n.y) * 0.25f,
                         (o.z + n.z) * 0.25f,
                         (o.w + n.w) * 0.25f);
}

extern "C" void kernel_launch(void* const* d_in, const int* in_sizes, int n_in,
                              void* d_out, int out_size, void* d_ws, size_t ws_size,
                              hipStream_t stream) {
    const float* user_emb  = (const float*)d_in[0];
    const float* item_emb  = (const float*)d_in[1];
    const float* edge_vals = (const float*)d_in[2];
    const int*   edge_row  = (const int*)  d_in[3];
    const int*   edge_col  = (const int*)  d_in[4];
    float* out = (float*)d_out;

    // ping-pong node buffers in workspace: 38.4 MB each
    const size_t buf_bytes = (size_t)N_NODES * EMBED_DIM * sizeof(float);
    float* bufA = (float*)d_ws;
    float* bufB = (float*)((char*)d_ws + buf_bytes);

    const int blk = 256;
    const int grid_nodes = (N_TOT4 + blk - 1) / blk;                   // 9375
    const long edge_threads = (long)NUM_EDGES * 16;
    const int grid_edges = (int)((edge_threads + blk - 1) / blk);      // 250000

    // init: cur=A=emb, out=emb, next=B=0
    init_kernel<<<grid_nodes, blk, 0, stream>>>(
        (const float4*)user_emb, (const float4*)item_emb,
        (float4*)bufA, (float4*)bufB, (float4*)out);

    // layer 1: A -> B
    edge_kernel<<<grid_edges, blk, 0, stream>>>(edge_row, edge_col, edge_vals, bufA, bufB);
    update_kernel<<<grid_nodes, blk, 0, stream>>>((float4*)out, (const float4*)bufB, (float4*)bufA);

    // layer 2: B -> A
    edge_kernel<<<grid_edges, blk, 0, stream>>>(edge_row, edge_col, edge_vals, bufB, bufA);
    update_kernel<<<grid_nodes, blk, 0, stream>>>((float4*)out, (const float4*)bufA, (float4*)bufB);

    // layer 3: A -> B, final: out = (out + B) / 4
    edge_kernel<<<grid_edges, blk, 0, stream>>>(edge_row, edge_col, edge_vals, bufA, bufB);
    final_kernel<<<grid_nodes, blk, 0, stream>>>((float4*)out, (const float4*)bufB);
}

// Round 2
// 1671.816 us; speedup vs baseline: 6.1298x; 6.1298x over previous
//
#include <hip/hip_runtime.h>

#define NUM_USERS 100000
#define NUM_ITEMS 50000
#define N_NODES   150000   // NUM_USERS + NUM_ITEMS
#define EMBED_DIM 64
#define NUM_EDGES 4000000

#define N_USER4  (NUM_USERS * EMBED_DIM / 4)   // 1,600,000
#define N_TOT4   (N_NODES  * EMBED_DIM / 4)    // 2,400,000

#define SCAN_BLK  256
#define NBLK_SCAN ((N_NODES + SCAN_BLK - 1) / SCAN_BLK)   // 586

// ---------------------------------------------------------------------------
// init: cur = out = concat(user_emb, item_emb)
// ---------------------------------------------------------------------------
__global__ void init_kernel(const float4* __restrict__ ue,
                            const float4* __restrict__ ie,
                            float4* __restrict__ cur,
                            float4* __restrict__ out) {
    int i = blockIdx.x * blockDim.x + threadIdx.x;
    if (i >= N_TOT4) return;
    float4 v = (i < N_USER4) ? ue[i] : ie[i - N_USER4];
    cur[i] = v;
    out[i] = v;
}

__global__ void zero_counts(int* __restrict__ c) {
    int i = blockIdx.x * blockDim.x + threadIdx.x;
    if (i < N_NODES) c[i] = 0;
}

// histogram of row indices
__global__ void hist_kernel(const int* __restrict__ row, int* __restrict__ counts) {
    int e = blockIdx.x * blockDim.x + threadIdx.x;
    if (e >= NUM_EDGES) return;
    atomicAdd(&counts[row[e]], 1);
}

// per-block exclusive scan of counts -> partial (into row_ptr), block totals
__global__ void scanA(const int* __restrict__ counts,
                      int* __restrict__ partial,
                      int* __restrict__ blockSums) {
    __shared__ int lds[SCAN_BLK];
    int tid = threadIdx.x;
    int i = blockIdx.x * SCAN_BLK + tid;
    int v = (i < N_NODES) ? counts[i] : 0;
    lds[tid] = v;
    __syncthreads();
    for (int off = 1; off < SCAN_BLK; off <<= 1) {
        int t = (tid >= off) ? lds[tid - off] : 0;
        __syncthreads();
        lds[tid] += t;
        __syncthreads();
    }
    int incl = lds[tid];
    if (i < N_NODES) partial[i] = incl - v;   // exclusive within block
    if (tid == SCAN_BLK - 1) blockSums[blockIdx.x] = incl;
}

// single-block exclusive scan of the 586 block totals
__global__ void scanB(int* __restrict__ blockSums) {
    __shared__ int lds[1024];
    int tid = threadIdx.x;
    int v = (tid < NBLK_SCAN) ? blockSums[tid] : 0;
    lds[tid] = v;
    __syncthreads();
    for (int off = 1; off < 1024; off <<= 1) {
        int t = (tid >= off) ? lds[tid - off] : 0;
        __syncthreads();
        lds[tid] += t;
        __syncthreads();
    }
    if (tid < NBLK_SCAN) blockSums[tid] = lds[tid] - v;  // exclusive
}

// finalize row_ptr = partial + blockOff; cursor = row_ptr; row_ptr[N]=E
__global__ void scanC(int* __restrict__ row_ptr,
                      const int* __restrict__ blockSums,
                      int* __restrict__ cursor) {
    int i = blockIdx.x * SCAN_BLK + threadIdx.x;
    if (i < N_NODES) {
        int rp = row_ptr[i] + blockSums[blockIdx.x];
        row_ptr[i] = rp;
        cursor[i]  = rp;
    }
    if (i == 0) row_ptr[N_NODES] = NUM_EDGES;
}

// permute edges into row-grouped packed (col, val)
__global__ void scatter_kernel(const int*   __restrict__ row,
                               const int*   __restrict__ col,
                               const float* __restrict__ val,
                               int* __restrict__ cursor,
                               int2* __restrict__ packed) {
    int e = blockIdx.x * blockDim.x + threadIdx.x;
    if (e >= NUM_EDGES) return;
    int r = row[e];
    int pos = atomicAdd(&cursor[r], 1);
    packed[pos] = make_int2(col[e], __float_as_int(val[e]));
}

// ---------------------------------------------------------------------------
// SpMM gather: one wave (64 lanes) per row, lane = embed dim
// ---------------------------------------------------------------------------
__global__ void spmm_kernel(const int*  __restrict__ row_ptr,
                            const int2* __restrict__ packed,
                            const float* __restrict__ x,
                            float*       __restrict__ y) {
    int gid  = blockIdx.x * blockDim.x + threadIdx.x;
    int wid  = gid >> 6;           // row
    int lane = gid & 63;           // embed dim
    if (wid >= N_NODES) return;
    int s = row_ptr[wid];
    int e = row_ptr[wid + 1];
    float acc = 0.f;
    for (int i = s; i < e; ++i) {
        int2 p = packed[i];                       // broadcast 8B
        acc += __int_as_float(p.y) * x[((long)p.x << 6) + lane];
    }
    y[((long)wid << 6) + lane] = acc;
}

// out += nxt
__global__ void update_kernel(float4* __restrict__ out,
                              const float4* __restrict__ nxt) {
    int i = blockIdx.x * blockDim.x + threadIdx.x;
    if (i >= N_TOT4) return;
    float4 o = out[i], n = nxt[i];
    o.x += n.x; o.y += n.y; o.z += n.z; o.w += n.w;
    out[i] = o;
}

// out = (out + nxt) * 0.25
__global__ void final_kernel(float4* __restrict__ out,
                             const float4* __restrict__ nxt) {
    int i = blockIdx.x * blockDim.x + threadIdx.x;
    if (i >= N_TOT4) return;
    float4 o = out[i], n = nxt[i];
    out[i] = make_float4((o.x + n.x) * 0.25f, (o.y + n.y) * 0.25f,
                         (o.z + n.z) * 0.25f, (o.w + n.w) * 0.25f);
}

// ------------------- fallback (round-1 atomic path) -------------------------
__global__ void edge_kernel(const int*   __restrict__ row,
                            const int*   __restrict__ col,
                            const float* __restrict__ val,
                            const float* __restrict__ x,
                            float*       __restrict__ y) {
    long gid = (long)blockIdx.x * blockDim.x + threadIdx.x;
    int e = (int)(gid >> 4);
    if (e >= NUM_EDGES) return;
    int d = ((int)gid & 15) * 4;
    int   r = row[e];
    int   c = col[e];
    float v = val[e];
    const float4 xv = *(const float4*)(x + (long)c * EMBED_DIM + d);
    float* yp = y + (long)r * EMBED_DIM + d;
    atomicAdd(yp + 0, v * xv.x);
    atomicAdd(yp + 1, v * xv.y);
    atomicAdd(yp + 2, v * xv.z);
    atomicAdd(yp + 3, v * xv.w);
}

__global__ void zero_buf_kernel(float4* __restrict__ b) {
    int i = blockIdx.x * blockDim.x + threadIdx.x;
    if (i < N_TOT4) b[i] = make_float4(0.f, 0.f, 0.f, 0.f);
}

extern "C" void kernel_launch(void* const* d_in, const int* in_sizes, int n_in,
                              void* d_out, int out_size, void* d_ws, size_t ws_size,
                              hipStream_t stream) {
    const float* user_emb  = (const float*)d_in[0];
    const float* item_emb  = (const float*)d_in[1];
    const float* edge_vals = (const float*)d_in[2];
    const int*   edge_row  = (const int*)  d_in[3];
    const int*   edge_col  = (const int*)  d_in[4];
    float* out = (float*)d_out;

    const size_t BUF = (size_t)N_NODES * EMBED_DIM * sizeof(float);   // 38.4 MB
    float* bufA = (float*)d_ws;
    float* bufB = (float*)((char*)d_ws + BUF);

    const int blk = 256;
    const int grid_nodes = (N_TOT4 + blk - 1) / blk;          // 9375
    const int grid_edges = (NUM_EDGES + blk - 1) / blk;       // 15625
    const int grid_spmm  = (N_NODES * 64 + blk - 1) / blk;    // 37500

    const size_t PACKED = (size_t)NUM_EDGES * sizeof(int2);   // 32 MB
    const size_t RP     = 600064;                             // (N_NODES+1)*4 padded
    const size_t need   = 2 * BUF + PACKED + 2 * RP + 4096;

    if (ws_size >= need) {
        int2* packed   = (int2*)((char*)d_ws + 2 * BUF);
        int*  row_ptr  = (int*) ((char*)d_ws + 2 * BUF + PACKED);
        int*  cursor   = (int*) ((char*)d_ws + 2 * BUF + PACKED + RP);
        int*  blockSum = (int*) ((char*)d_ws + 2 * BUF + PACKED + 2 * RP);

        init_kernel<<<grid_nodes, blk, 0, stream>>>(
            (const float4*)user_emb, (const float4*)item_emb,
            (float4*)bufA, (float4*)out);

        // --- build CSR (counts live in `cursor` during hist/scan) ---
        zero_counts<<<NBLK_SCAN, SCAN_BLK, 0, stream>>>(cursor);
        hist_kernel<<<grid_edges, blk, 0, stream>>>(edge_row, cursor);
        scanA<<<NBLK_SCAN, SCAN_BLK, 0, stream>>>(cursor, row_ptr, blockSum);
        scanB<<<1, 1024, 0, stream>>>(blockSum);
        scanC<<<NBLK_SCAN, SCAN_BLK, 0, stream>>>(row_ptr, blockSum, cursor);
        scatter_kernel<<<grid_edges, blk, 0, stream>>>(edge_row, edge_col, edge_vals,
                                                       cursor, packed);

        // --- 3 propagation layers, gather form (no fp32 atomics) ---
        spmm_kernel<<<grid_spmm, blk, 0, stream>>>(row_ptr, packed, bufA, bufB);
        update_kernel<<<grid_nodes, blk, 0, stream>>>((float4*)out, (const float4*)bufB);

        spmm_kernel<<<grid_spmm, blk, 0, stream>>>(row_ptr, packed, bufB, bufA);
        update_kernel<<<grid_nodes, blk, 0, stream>>>((float4*)out, (const float4*)bufA);

        spmm_kernel<<<grid_spmm, blk, 0, stream>>>(row_ptr, packed, bufA, bufB);
        final_kernel<<<grid_nodes, blk, 0, stream>>>((float4*)out, (const float4*)bufB);
    } else {
        // fallback: round-1 atomic scatter path (needs only 76.8 MB)
        const long edge_threads = (long)NUM_EDGES * 16;
        const int grid_edges16 = (int)((edge_threads + blk - 1) / blk);

        init_kernel<<<grid_nodes, blk, 0, stream>>>(
            (const float4*)user_emb, (const float4*)item_emb,
            (float4*)bufA, (float4*)out);
        zero_buf_kernel<<<grid_nodes, blk, 0, stream>>>((float4*)bufB);

        edge_kernel<<<grid_edges16, blk, 0, stream>>>(edge_row, edge_col, edge_vals, bufA, bufB);
        update_kernel<<<grid_nodes, blk, 0, stream>>>((float4*)out, (const float4*)bufB);
        zero_buf_kernel<<<grid_nodes, blk, 0, stream>>>((float4*)bufA);

        edge_kernel<<<grid_edges16, blk, 0, stream>>>(edge_row, edge_col, edge_vals, bufB, bufA);
        update_kernel<<<grid_nodes, blk, 0, stream>>>((float4*)out, (const float4*)bufA);
        zero_buf_kernel<<<grid_nodes, blk, 0, stream>>>((float4*)bufB);

        edge_kernel<<<grid_edges16, blk, 0, stream>>>(edge_row, edge_col, edge_vals, bufA, bufB);
        final_kernel<<<grid_nodes, blk, 0, stream>>>((float4*)out, (const float4*)bufB);
    }
}

// Round 3
// 1056.684 us; speedup vs baseline: 9.6982x; 1.5821x over previous
//
#include <hip/hip_runtime.h>

#define NUM_USERS 100000
#define NUM_ITEMS 50000
#define N_NODES   150000   // NUM_USERS + NUM_ITEMS
#define EMBED_DIM 64
#define NUM_EDGES 4000000

#define N_USER4  (NUM_USERS * EMBED_DIM / 4)   // 1,600,000
#define N_TOT4   (N_NODES  * EMBED_DIM / 4)    // 2,400,000

#define SCAN_BLK  256
#define NBLK_SCAN ((N_NODES + SCAN_BLK - 1) / SCAN_BLK)   // 586

// ---------------------------------------------------------------------------
// init: cur = out = concat(user_emb, item_emb)
// ---------------------------------------------------------------------------
__global__ void init_kernel(const float4* __restrict__ ue,
                            const float4* __restrict__ ie,
                            float4* __restrict__ cur,
                            float4* __restrict__ out) {
    int i = blockIdx.x * blockDim.x + threadIdx.x;
    if (i >= N_TOT4) return;
    float4 v = (i < N_USER4) ? ue[i] : ie[i - N_USER4];
    cur[i] = v;
    out[i] = v;
}

__global__ void zero_counts(int* __restrict__ c) {
    int i = blockIdx.x * blockDim.x + threadIdx.x;
    if (i < N_NODES) c[i] = 0;
}

// histogram of row indices
__global__ void hist_kernel(const int* __restrict__ row, int* __restrict__ counts) {
    int e = blockIdx.x * blockDim.x + threadIdx.x;
    if (e >= NUM_EDGES) return;
    atomicAdd(&counts[row[e]], 1);
}

// per-block exclusive scan of counts -> partial (into row_ptr), block totals
__global__ void scanA(const int* __restrict__ counts,
                      int* __restrict__ partial,
                      int* __restrict__ blockSums) {
    __shared__ int lds[SCAN_BLK];
    int tid = threadIdx.x;
    int i = blockIdx.x * SCAN_BLK + tid;
    int v = (i < N_NODES) ? counts[i] : 0;
    lds[tid] = v;
    __syncthreads();
    for (int off = 1; off < SCAN_BLK; off <<= 1) {
        int t = (tid >= off) ? lds[tid - off] : 0;
        __syncthreads();
        lds[tid] += t;
        __syncthreads();
    }
    int incl = lds[tid];
    if (i < N_NODES) partial[i] = incl - v;   // exclusive within block
    if (tid == SCAN_BLK - 1) blockSums[blockIdx.x] = incl;
}

// single-block exclusive scan of the 586 block totals
__global__ void scanB(int* __restrict__ blockSums) {
    __shared__ int lds[1024];
    int tid = threadIdx.x;
    int v = (tid < NBLK_SCAN) ? blockSums[tid] : 0;
    lds[tid] = v;
    __syncthreads();
    for (int off = 1; off < 1024; off <<= 1) {
        int t = (tid >= off) ? lds[tid - off] : 0;
        __syncthreads();
        lds[tid] += t;
        __syncthreads();
    }
    if (tid < NBLK_SCAN) blockSums[tid] = lds[tid] - v;  // exclusive
}

// finalize row_ptr = partial + blockOff; cursor = row_ptr; row_ptr[N]=E
__global__ void scanC(int* __restrict__ row_ptr,
                      const int* __restrict__ blockSums,
                      int* __restrict__ cursor) {
    int i = blockIdx.x * SCAN_BLK + threadIdx.x;
    if (i < N_NODES) {
        int rp = row_ptr[i] + blockSums[blockIdx.x];
        row_ptr[i] = rp;
        cursor[i]  = rp;
    }
    if (i == 0) row_ptr[N_NODES] = NUM_EDGES;
}

// permute edges into row-grouped packed (col, val)
__global__ void scatter_kernel(const int*   __restrict__ row,
                               const int*   __restrict__ col,
                               const float* __restrict__ val,
                               int* __restrict__ cursor,
                               int2* __restrict__ packed) {
    int e = blockIdx.x * blockDim.x + threadIdx.x;
    if (e >= NUM_EDGES) return;
    int r = row[e];
    int pos = atomicAdd(&cursor[r], 1);
    packed[pos] = make_int2(col[e], __float_as_int(val[e]));
}

// ---------------------------------------------------------------------------
// SpMM gather: one wave (64 lanes) per row, lane = embed dim.
// 4x manual unroll for memory-level parallelism (VGPR=8 round-2 evidence:
// compiler did not unroll; gather latency was exposed serially).
// MODE 0: y = acc, out += acc          (layers 1,2)
// MODE 1: out = (out + acc) * 0.25     (layer 3; y not written)
// ---------------------------------------------------------------------------
template <int MODE>
__global__ void spmm_kernel(const int*  __restrict__ row_ptr,
                            const int2* __restrict__ packed,
                            const float* __restrict__ x,
                            float*       __restrict__ y,
                            float*       __restrict__ out) {
    int gid  = blockIdx.x * blockDim.x + threadIdx.x;
    int wid  = gid >> 6;           // row
    int lane = gid & 63;           // embed dim
    if (wid >= N_NODES) return;
    int s = row_ptr[wid];
    int e = row_ptr[wid + 1];

    float acc0 = 0.f, acc1 = 0.f, acc2 = 0.f, acc3 = 0.f;
    int i = s;
    for (; i + 4 <= e; i += 4) {
        int2 p0 = packed[i + 0];
        int2 p1 = packed[i + 1];
        int2 p2 = packed[i + 2];
        int2 p3 = packed[i + 3];
        float x0 = x[((long)p0.x << 6) + lane];
        float x1 = x[((long)p1.x << 6) + lane];
        float x2 = x[((long)p2.x << 6) + lane];
        float x3 = x[((long)p3.x << 6) + lane];
        acc0 += __int_as_float(p0.y) * x0;
        acc1 += __int_as_float(p1.y) * x1;
        acc2 += __int_as_float(p2.y) * x2;
        acc3 += __int_as_float(p3.y) * x3;
    }
    for (; i < e; ++i) {
        int2 p = packed[i];
        acc0 += __int_as_float(p.y) * x[((long)p.x << 6) + lane];
    }
    float acc = (acc0 + acc1) + (acc2 + acc3);

    long o = ((long)wid << 6) + lane;
    if (MODE == 0) {
        y[o] = acc;
        out[o] += acc;
    } else {
        out[o] = (out[o] + acc) * 0.25f;
    }
}

// ------------------- fallback (round-1 atomic path) -------------------------
__global__ void edge_kernel(const int*   __restrict__ row,
                            const int*   __restrict__ col,
                            const float* __restrict__ val,
                            const float* __restrict__ x,
                            float*       __restrict__ y) {
    long gid = (long)blockIdx.x * blockDim.x + threadIdx.x;
    int e = (int)(gid >> 4);
    if (e >= NUM_EDGES) return;
    int d = ((int)gid & 15) * 4;
    int   r = row[e];
    int   c = col[e];
    float v = val[e];
    const float4 xv = *(const float4*)(x + (long)c * EMBED_DIM + d);
    float* yp = y + (long)r * EMBED_DIM + d;
    atomicAdd(yp + 0, v * xv.x);
    atomicAdd(yp + 1, v * xv.y);
    atomicAdd(yp + 2, v * xv.z);
    atomicAdd(yp + 3, v * xv.w);
}

__global__ void update_kernel(float4* __restrict__ out,
                              const float4* __restrict__ nxt) {
    int i = blockIdx.x * blockDim.x + threadIdx.x;
    if (i >= N_TOT4) return;
    float4 o = out[i], n = nxt[i];
    o.x += n.x; o.y += n.y; o.z += n.z; o.w += n.w;
    out[i] = o;
}

__global__ void final_kernel(float4* __restrict__ out,
                             const float4* __restrict__ nxt) {
    int i = blockIdx.x * blockDim.x + threadIdx.x;
    if (i >= N_TOT4) return;
    float4 o = out[i], n = nxt[i];
    out[i] = make_float4((o.x + n.x) * 0.25f, (o.y + n.y) * 0.25f,
                         (o.z + n.z) * 0.25f, (o.w + n.w) * 0.25f);
}

__global__ void zero_buf_kernel(float4* __restrict__ b) {
    int i = blockIdx.x * blockDim.x + threadIdx.x;
    if (i < N_TOT4) b[i] = make_float4(0.f, 0.f, 0.f, 0.f);
}

extern "C" void kernel_launch(void* const* d_in, const int* in_sizes, int n_in,
                              void* d_out, int out_size, void* d_ws, size_t ws_size,
                              hipStream_t stream) {
    const float* user_emb  = (const float*)d_in[0];
    const float* item_emb  = (const float*)d_in[1];
    const float* edge_vals = (const float*)d_in[2];
    const int*   edge_row  = (const int*)  d_in[3];
    const int*   edge_col  = (const int*)  d_in[4];
    float* out = (float*)d_out;

    const size_t BUF = (size_t)N_NODES * EMBED_DIM * sizeof(float);   // 38.4 MB
    float* bufA = (float*)d_ws;
    float* bufB = (float*)((char*)d_ws + BUF);

    const int blk = 256;
    const int grid_nodes = (N_TOT4 + blk - 1) / blk;          // 9375
    const int grid_edges = (NUM_EDGES + blk - 1) / blk;       // 15625
    const int grid_spmm  = (N_NODES * 64 + blk - 1) / blk;    // 37500

    const size_t PACKED = (size_t)NUM_EDGES * sizeof(int2);   // 32 MB
    const size_t RP     = 600064;                             // (N_NODES+1)*4 padded
    const size_t need   = 2 * BUF + PACKED + 2 * RP + 4096;

    if (ws_size >= need) {
        int2* packed   = (int2*)((char*)d_ws + 2 * BUF);
        int*  row_ptr  = (int*) ((char*)d_ws + 2 * BUF + PACKED);
        int*  cursor   = (int*) ((char*)d_ws + 2 * BUF + PACKED + RP);
        int*  blockSum = (int*) ((char*)d_ws + 2 * BUF + PACKED + 2 * RP);

        init_kernel<<<grid_nodes, blk, 0, stream>>>(
            (const float4*)user_emb, (const float4*)item_emb,
            (float4*)bufA, (float4*)out);

        // --- build CSR (counts live in `cursor` during hist/scan) ---
        zero_counts<<<NBLK_SCAN, SCAN_BLK, 0, stream>>>(cursor);
        hist_kernel<<<grid_edges, blk, 0, stream>>>(edge_row, cursor);
        scanA<<<NBLK_SCAN, SCAN_BLK, 0, stream>>>(cursor, row_ptr, blockSum);
        scanB<<<1, 1024, 0, stream>>>(blockSum);
        scanC<<<NBLK_SCAN, SCAN_BLK, 0, stream>>>(row_ptr, blockSum, cursor);
        scatter_kernel<<<grid_edges, blk, 0, stream>>>(edge_row, edge_col, edge_vals,
                                                       cursor, packed);

        // --- 3 propagation layers, gather form, fused epilogues ---
        spmm_kernel<0><<<grid_spmm, blk, 0, stream>>>(row_ptr, packed, bufA, bufB, out);
        spmm_kernel<0><<<grid_spmm, blk, 0, stream>>>(row_ptr, packed, bufB, bufA, out);
        spmm_kernel<1><<<grid_spmm, blk, 0, stream>>>(row_ptr, packed, bufA, bufB, out);
    } else {
        // fallback: round-1 atomic scatter path (needs only 76.8 MB)
        const long edge_threads = (long)NUM_EDGES * 16;
        const int grid_edges16 = (int)((edge_threads + blk - 1) / blk);

        init_kernel<<<grid_nodes, blk, 0, stream>>>(
            (const float4*)user_emb, (const float4*)item_emb,
            (float4*)bufA, (float4*)out);
        zero_buf_kernel<<<grid_nodes, blk, 0, stream>>>((float4*)bufB);

        edge_kernel<<<grid_edges16, blk, 0, stream>>>(edge_row, edge_col, edge_vals, bufA, bufB);
        update_kernel<<<grid_nodes, blk, 0, stream>>>((float4*)out, (const float4*)bufB);
        zero_buf_kernel<<<grid_nodes, blk, 0, stream>>>((float4*)bufA);

        edge_kernel<<<grid_edges16, blk, 0, stream>>>(edge_row, edge_col, edge_vals, bufB, bufA);
        update_kernel<<<grid_nodes, blk, 0, stream>>>((float4*)out, (const float4*)bufA);
        zero_buf_kernel<<<grid_nodes, blk, 0, stream>>>((float4*)bufB);

        edge_kernel<<<grid_edges16, blk, 0, stream>>>(edge_row, edge_col, edge_vals, bufA, bufB);
        final_kernel<<<grid_nodes, blk, 0, stream>>>((float4*)out, (const float4*)bufB);
    }
}

// Round 4
// 913.697 us; speedup vs baseline: 11.2159x; 1.1565x over previous
//
#include <hip/hip_runtime.h>

#define NUM_USERS 100000
#define NUM_ITEMS 50000
#define N_NODES   150000   // NUM_USERS + NUM_ITEMS
#define EMBED_DIM 64
#define NUM_EDGES 4000000

#define N_USER4  (NUM_USERS * EMBED_DIM / 4)   // 1,600,000
#define N_TOT4   (N_NODES  * EMBED_DIM / 4)    // 2,400,000

#define SCAN_BLK  256
#define NBLK_SCAN ((N_NODES + SCAN_BLK - 1) / SCAN_BLK)   // 586

#define NXCD        8
#define ROWS_PER_X  ((N_NODES + NXCD - 1) / NXCD)         // 18750

// ---------------------------------------------------------------------------
// init: cur = out = concat(user_emb, item_emb)
// ---------------------------------------------------------------------------
__global__ void init_kernel(const float4* __restrict__ ue,
                            const float4* __restrict__ ie,
                            float4* __restrict__ cur,
                            float4* __restrict__ out) {
    int i = blockIdx.x * blockDim.x + threadIdx.x;
    if (i >= N_TOT4) return;
    float4 v = (i < N_USER4) ? ue[i] : ie[i - N_USER4];
    cur[i] = v;
    out[i] = v;
}

__global__ void zero_counts(int* __restrict__ c) {
    int i = blockIdx.x * blockDim.x + threadIdx.x;
    if (i < N_NODES) c[i] = 0;
}

// histogram of row indices
__global__ void hist_kernel(const int* __restrict__ row, int* __restrict__ counts) {
    int e = blockIdx.x * blockDim.x + threadIdx.x;
    if (e >= NUM_EDGES) return;
    atomicAdd(&counts[row[e]], 1);
}

// per-block exclusive scan of counts -> partial (into row_ptr), block totals
__global__ void scanA(const int* __restrict__ counts,
                      int* __restrict__ partial,
                      int* __restrict__ blockSums) {
    __shared__ int lds[SCAN_BLK];
    int tid = threadIdx.x;
    int i = blockIdx.x * SCAN_BLK + tid;
    int v = (i < N_NODES) ? counts[i] : 0;
    lds[tid] = v;
    __syncthreads();
    for (int off = 1; off < SCAN_BLK; off <<= 1) {
        int t = (tid >= off) ? lds[tid - off] : 0;
        __syncthreads();
        lds[tid] += t;
        __syncthreads();
    }
    int incl = lds[tid];
    if (i < N_NODES) partial[i] = incl - v;
    if (tid == SCAN_BLK - 1) blockSums[blockIdx.x] = incl;
}

// single-block exclusive scan of the 586 block totals
__global__ void scanB(int* __restrict__ blockSums) {
    __shared__ int lds[1024];
    int tid = threadIdx.x;
    int v = (tid < NBLK_SCAN) ? blockSums[tid] : 0;
    lds[tid] = v;
    __syncthreads();
    for (int off = 1; off < 1024; off <<= 1) {
        int t = (tid >= off) ? lds[tid - off] : 0;
        __syncthreads();
        lds[tid] += t;
        __syncthreads();
    }
    if (tid < NBLK_SCAN) blockSums[tid] = lds[tid] - v;
}

// finalize row_ptr = partial + blockOff; cursor = row_ptr; row_ptr[N]=E
__global__ void scanC(int* __restrict__ row_ptr,
                      const int* __restrict__ blockSums,
                      int* __restrict__ cursor) {
    int i = blockIdx.x * SCAN_BLK + threadIdx.x;
    if (i < N_NODES) {
        int rp = row_ptr[i] + blockSums[blockIdx.x];
        row_ptr[i] = rp;
        cursor[i]  = rp;
    }
    if (i == 0) row_ptr[N_NODES] = NUM_EDGES;
}

// ---------------------------------------------------------------------------
// XCD-windowed scatter: blockIdx&7 selects an XCD class (round-robin dispatch
// heuristic). Each class sweeps ALL edges, claims only rows in its ~18750-row
// range, so its int2 writes land in a ~4.3 MB window that fits the XCD's L2
// and partial lines merge before write-back. (Round-3 evidence: random 8B
// scatter produced 247 MB WRITE_SIZE for a 32 MB array.)
// ---------------------------------------------------------------------------
__global__ void scatter_kernel(const int*   __restrict__ row,
                               const int*   __restrict__ col,
                               const float* __restrict__ val,
                               int* __restrict__ cursor,
                               int2* __restrict__ packed) {
    int xcd   = blockIdx.x & (NXCD - 1);
    int slice = blockIdx.x >> 3;
    int nsl   = gridDim.x >> 3;
    int rlo = xcd * ROWS_PER_X;
    int rhi = rlo + ROWS_PER_X; if (rhi > N_NODES) rhi = N_NODES;

    int stride = nsl * blockDim.x;
    for (int e = slice * blockDim.x + threadIdx.x; e < NUM_EDGES; e += stride) {
        int r = row[e];
        if (r >= rlo && r < rhi) {
            int pos = atomicAdd(&cursor[r], 1);
            packed[pos] = make_int2(col[e], __float_as_int(val[e]));
        }
    }
}

// ---------------------------------------------------------------------------
// SpMM gather: one wave per row, lane = embed dim.
// Wave-cooperative edge fetch: lane i loads packed[base+i] (coalesced), then
// the j-loop broadcasts (col,val) via v_readlane (uniform j -> SGPR), 8-deep
// gather groups for memory-level parallelism. Kills the 4M wave-uniform 8B
// VMEM transactions per layer of rounds 2-3.
// MODE 0: y = acc, out += acc          (layers 1,2)
// MODE 1: out = (out + acc) * 0.25     (layer 3; y not written)
// ---------------------------------------------------------------------------
template <int MODE>
__global__ void spmm_kernel(const int*  __restrict__ row_ptr,
                            const int2* __restrict__ packed,
                            const float* __restrict__ x,
                            float*       __restrict__ y,
                            float*       __restrict__ out) {
    int gid  = blockIdx.x * blockDim.x + threadIdx.x;
    int wid  = gid >> 6;           // row
    int lane = gid & 63;           // embed dim
    if (wid >= N_NODES) return;
    int s = row_ptr[wid];
    int e = row_ptr[wid + 1];

    float acc0 = 0.f, acc1 = 0.f, acc2 = 0.f, acc3 = 0.f;
    float acc4 = 0.f, acc5 = 0.f, acc6 = 0.f, acc7 = 0.f;

    for (int base = s; base < e; base += 64) {
        int idx = base + lane;
        int2 pk = make_int2(0, 0);
        if (idx < e) pk = packed[idx];          // one coalesced 512B txn / 64 edges
        int m = e - base; if (m > 64) m = 64;

        int j = 0;
        for (; j + 8 <= m; j += 8) {
            int   c0 = __builtin_amdgcn_readlane(pk.x, j + 0);
            int   c1 = __builtin_amdgcn_readlane(pk.x, j + 1);
            int   c2 = __builtin_amdgcn_readlane(pk.x, j + 2);
            int   c3 = __builtin_amdgcn_readlane(pk.x, j + 3);
            int   c4 = __builtin_amdgcn_readlane(pk.x, j + 4);
            int   c5 = __builtin_amdgcn_readlane(pk.x, j + 5);
            int   c6 = __builtin_amdgcn_readlane(pk.x, j + 6);
            int   c7 = __builtin_amdgcn_readlane(pk.x, j + 7);
            float x0 = x[((long)c0 << 6) + lane];
            float x1 = x[((long)c1 << 6) + lane];
            float x2 = x[((long)c2 << 6) + lane];
            float x3 = x[((long)c3 << 6) + lane];
            float x4 = x[((long)c4 << 6) + lane];
            float x5 = x[((long)c5 << 6) + lane];
            float x6 = x[((long)c6 << 6) + lane];
            float x7 = x[((long)c7 << 6) + lane];
            float v0 = __int_as_float(__builtin_amdgcn_readlane(pk.y, j + 0));
            float v1 = __int_as_float(__builtin_amdgcn_readlane(pk.y, j + 1));
            float v2 = __int_as_float(__builtin_amdgcn_readlane(pk.y, j + 2));
            float v3 = __int_as_float(__builtin_amdgcn_readlane(pk.y, j + 3));
            float v4 = __int_as_float(__builtin_amdgcn_readlane(pk.y, j + 4));
            float v5 = __int_as_float(__builtin_amdgcn_readlane(pk.y, j + 5));
            float v6 = __int_as_float(__builtin_amdgcn_readlane(pk.y, j + 6));
            float v7 = __int_as_float(__builtin_amdgcn_readlane(pk.y, j + 7));
            acc0 = fmaf(v0, x0, acc0);
            acc1 = fmaf(v1, x1, acc1);
            acc2 = fmaf(v2, x2, acc2);
            acc3 = fmaf(v3, x3, acc3);
            acc4 = fmaf(v4, x4, acc4);
            acc5 = fmaf(v5, x5, acc5);
            acc6 = fmaf(v6, x6, acc6);
            acc7 = fmaf(v7, x7, acc7);
        }
        for (; j < m; ++j) {
            int   c = __builtin_amdgcn_readlane(pk.x, j);
            float v = __int_as_float(__builtin_amdgcn_readlane(pk.y, j));
            acc0 = fmaf(v, x[((long)c << 6) + lane], acc0);
        }
    }
    float acc = ((acc0 + acc1) + (acc2 + acc3)) + ((acc4 + acc5) + (acc6 + acc7));

    long o = ((long)wid << 6) + lane;
    if (MODE == 0) {
        y[o] = acc;
        out[o] += acc;
    } else {
        out[o] = (out[o] + acc) * 0.25f;
    }
}

// ------------------- fallback (round-1 atomic path) -------------------------
__global__ void edge_kernel(const int*   __restrict__ row,
                            const int*   __restrict__ col,
                            const float* __restrict__ val,
                            const float* __restrict__ x,
                            float*       __restrict__ y) {
    long gid = (long)blockIdx.x * blockDim.x + threadIdx.x;
    int e = (int)(gid >> 4);
    if (e >= NUM_EDGES) return;
    int d = ((int)gid & 15) * 4;
    int   r = row[e];
    int   c = col[e];
    float v = val[e];
    const float4 xv = *(const float4*)(x + (long)c * EMBED_DIM + d);
    float* yp = y + (long)r * EMBED_DIM + d;
    atomicAdd(yp + 0, v * xv.x);
    atomicAdd(yp + 1, v * xv.y);
    atomicAdd(yp + 2, v * xv.z);
    atomicAdd(yp + 3, v * xv.w);
}

__global__ void update_kernel(float4* __restrict__ out,
                              const float4* __restrict__ nxt) {
    int i = blockIdx.x * blockDim.x + threadIdx.x;
    if (i >= N_TOT4) return;
    float4 o = out[i], n = nxt[i];
    o.x += n.x; o.y += n.y; o.z += n.z; o.w += n.w;
    out[i] = o;
}

__global__ void final_kernel(float4* __restrict__ out,
                             const float4* __restrict__ nxt) {
    int i = blockIdx.x * blockDim.x + threadIdx.x;
    if (i >= N_TOT4) return;
    float4 o = out[i], n = nxt[i];
    out[i] = make_float4((o.x + n.x) * 0.25f, (o.y + n.y) * 0.25f,
                         (o.z + n.z) * 0.25f, (o.w + n.w) * 0.25f);
}

__global__ void zero_buf_kernel(float4* __restrict__ b) {
    int i = blockIdx.x * blockDim.x + threadIdx.x;
    if (i < N_TOT4) b[i] = make_float4(0.f, 0.f, 0.f, 0.f);
}

extern "C" void kernel_launch(void* const* d_in, const int* in_sizes, int n_in,
                              void* d_out, int out_size, void* d_ws, size_t ws_size,
                              hipStream_t stream) {
    const float* user_emb  = (const float*)d_in[0];
    const float* item_emb  = (const float*)d_in[1];
    const float* edge_vals = (const float*)d_in[2];
    const int*   edge_row  = (const int*)  d_in[3];
    const int*   edge_col  = (const int*)  d_in[4];
    float* out = (float*)d_out;

    const size_t BUF = (size_t)N_NODES * EMBED_DIM * sizeof(float);   // 38.4 MB
    float* bufA = (float*)d_ws;
    float* bufB = (float*)((char*)d_ws + BUF);

    const int blk = 256;
    const int grid_nodes = (N_TOT4 + blk - 1) / blk;          // 9375
    const int grid_edges = (NUM_EDGES + blk - 1) / blk;       // 15625
    const int grid_spmm  = (N_NODES * 64 + blk - 1) / blk;    // 37500
    const int grid_scat  = 2048;                              // 8 classes x 256 slices

    const size_t PACKED = (size_t)NUM_EDGES * sizeof(int2);   // 32 MB
    const size_t RP     = 600064;                             // (N_NODES+1)*4 padded
    const size_t need   = 2 * BUF + PACKED + 2 * RP + 4096;

    if (ws_size >= need) {
        int2* packed   = (int2*)((char*)d_ws + 2 * BUF);
        int*  row_ptr  = (int*) ((char*)d_ws + 2 * BUF + PACKED);
        int*  cursor   = (int*) ((char*)d_ws + 2 * BUF + PACKED + RP);
        int*  blockSum = (int*) ((char*)d_ws + 2 * BUF + PACKED + 2 * RP);

        init_kernel<<<grid_nodes, blk, 0, stream>>>(
            (const float4*)user_emb, (const float4*)item_emb,
            (float4*)bufA, (float4*)out);

        // --- build CSR (counts live in `cursor` during hist/scan) ---
        zero_counts<<<NBLK_SCAN, SCAN_BLK, 0, stream>>>(cursor);
        hist_kernel<<<grid_edges, blk, 0, stream>>>(edge_row, cursor);
        scanA<<<NBLK_SCAN, SCAN_BLK, 0, stream>>>(cursor, row_ptr, blockSum);
        scanB<<<1, 1024, 0, stream>>>(blockSum);
        scanC<<<NBLK_SCAN, SCAN_BLK, 0, stream>>>(row_ptr, blockSum, cursor);
        scatter_kernel<<<grid_scat, blk, 0, stream>>>(edge_row, edge_col, edge_vals,
                                                      cursor, packed);

        // --- 3 propagation layers, gather form, fused epilogues ---
        spmm_kernel<0><<<grid_spmm, blk, 0, stream>>>(row_ptr, packed, bufA, bufB, out);
        spmm_kernel<0><<<grid_spmm, blk, 0, stream>>>(row_ptr, packed, bufB, bufA, out);
        spmm_kernel<1><<<grid_spmm, blk, 0, stream>>>(row_ptr, packed, bufA, bufB, out);
    } else {
        // fallback: round-1 atomic scatter path (needs only 76.8 MB)
        const long edge_threads = (long)NUM_EDGES * 16;
        const int grid_edges16 = (int)((edge_threads + blk - 1) / blk);

        init_kernel<<<grid_nodes, blk, 0, stream>>>(
            (const float4*)user_emb, (const float4*)item_emb,
            (float4*)bufA, (float4*)out);
        zero_buf_kernel<<<grid_nodes, blk, 0, stream>>>((float4*)bufB);

        edge_kernel<<<grid_edges16, blk, 0, stream>>>(edge_row, edge_col, edge_vals, bufA, bufB);
        update_kernel<<<grid_nodes, blk, 0, stream>>>((float4*)out, (const float4*)bufB);
        zero_buf_kernel<<<grid_nodes, blk, 0, stream>>>((float4*)bufA);

        edge_kernel<<<grid_edges16, blk, 0, stream>>>(edge_row, edge_col, edge_vals, bufB, bufA);
        update_kernel<<<grid_nodes, blk, 0, stream>>>((float4*)out, (const float4*)bufA);
        zero_buf_kernel<<<grid_nodes, blk, 0, stream>>>((float4*)bufB);

        edge_kernel<<<grid_edges16, blk, 0, stream>>>(edge_row, edge_col, edge_vals, bufA, bufB);
        final_kernel<<<grid_nodes, blk, 0, stream>>>((float4*)out, (const float4*)bufB);
    }
}

// Round 5
// 776.234 us; speedup vs baseline: 13.2021x; 1.1771x over previous
//
#include <hip/hip_runtime.h>

#define NUM_USERS 100000
#define NUM_ITEMS 50000
#define N_NODES   150000   // NUM_USERS + NUM_ITEMS
#define EMBED_DIM 64
#define NUM_EDGES 4000000

#define N_USER4  (NUM_USERS * EMBED_DIM / 4)   // 1,600,000
#define N_TOT4   (N_NODES  * EMBED_DIM / 4)    // 2,400,000

#define SCAN_BLK  256
#define NBLK_SCAN ((N_NODES + SCAN_BLK - 1) / SCAN_BLK)   // 586

#define NXCD        8
#define ROWS_PER_X  ((N_NODES + NXCD - 1) / NXCD)         // 18750

// bf16 helpers: store with round-to-nearest-even, load with shift (exact)
__device__ __forceinline__ unsigned short f2bf(float f) {
    unsigned int u = __float_as_uint(f);
    u = (u + 0x7fffu + ((u >> 16) & 1u)) >> 16;
    return (unsigned short)u;
}
__device__ __forceinline__ float bf2f(unsigned short b) {
    return __uint_as_float((unsigned int)b << 16);
}

// ---------------------------------------------------------------------------
// init: cur(bf16) = emb; out(fp32) = emb
// ---------------------------------------------------------------------------
__global__ void init_kernel(const float4* __restrict__ ue,
                            const float4* __restrict__ ie,
                            ushort4* __restrict__ cur_bf,
                            float4*  __restrict__ out) {
    int i = blockIdx.x * blockDim.x + threadIdx.x;
    if (i >= N_TOT4) return;
    float4 v = (i < N_USER4) ? ue[i] : ie[i - N_USER4];
    out[i] = v;
    ushort4 b;
    b.x = f2bf(v.x); b.y = f2bf(v.y); b.z = f2bf(v.z); b.w = f2bf(v.w);
    cur_bf[i] = b;
}

__global__ void zero_counts(int* __restrict__ c) {
    int i = blockIdx.x * blockDim.x + threadIdx.x;
    if (i < N_NODES) c[i] = 0;
}

// histogram of row indices
__global__ void hist_kernel(const int* __restrict__ row, int* __restrict__ counts) {
    int e = blockIdx.x * blockDim.x + threadIdx.x;
    if (e >= NUM_EDGES) return;
    atomicAdd(&counts[row[e]], 1);
}

// per-block exclusive scan of counts -> partial (into row_ptr), block totals
__global__ void scanA(const int* __restrict__ counts,
                      int* __restrict__ partial,
                      int* __restrict__ blockSums) {
    __shared__ int lds[SCAN_BLK];
    int tid = threadIdx.x;
    int i = blockIdx.x * SCAN_BLK + tid;
    int v = (i < N_NODES) ? counts[i] : 0;
    lds[tid] = v;
    __syncthreads();
    for (int off = 1; off < SCAN_BLK; off <<= 1) {
        int t = (tid >= off) ? lds[tid - off] : 0;
        __syncthreads();
        lds[tid] += t;
        __syncthreads();
    }
    int incl = lds[tid];
    if (i < N_NODES) partial[i] = incl - v;
    if (tid == SCAN_BLK - 1) blockSums[blockIdx.x] = incl;
}

// single-block exclusive scan of the 586 block totals
__global__ void scanB(int* __restrict__ blockSums) {
    __shared__ int lds[1024];
    int tid = threadIdx.x;
    int v = (tid < NBLK_SCAN) ? blockSums[tid] : 0;
    lds[tid] = v;
    __syncthreads();
    for (int off = 1; off < 1024; off <<= 1) {
        int t = (tid >= off) ? lds[tid - off] : 0;
        __syncthreads();
        lds[tid] += t;
        __syncthreads();
    }
    if (tid < NBLK_SCAN) blockSums[tid] = lds[tid] - v;
}

// finalize row_ptr = partial + blockOff; cursor = row_ptr; row_ptr[N]=E
__global__ void scanC(int* __restrict__ row_ptr,
                      const int* __restrict__ blockSums,
                      int* __restrict__ cursor) {
    int i = blockIdx.x * SCAN_BLK + threadIdx.x;
    if (i < N_NODES) {
        int rp = row_ptr[i] + blockSums[blockIdx.x];
        row_ptr[i] = rp;
        cursor[i]  = rp;
    }
    if (i == 0) row_ptr[N_NODES] = NUM_EDGES;
}

// XCD-windowed scatter (round-4 version; 2-pass LDS rework is the round-6 play)
__global__ void scatter_kernel(const int*   __restrict__ row,
                               const int*   __restrict__ col,
                               const float* __restrict__ val,
                               int* __restrict__ cursor,
                               int2* __restrict__ packed) {
    int xcd   = blockIdx.x & (NXCD - 1);
    int slice = blockIdx.x >> 3;
    int nsl   = gridDim.x >> 3;
    int rlo = xcd * ROWS_PER_X;
    int rhi = rlo + ROWS_PER_X; if (rhi > N_NODES) rhi = N_NODES;

    int stride = nsl * blockDim.x;
    for (int e = slice * blockDim.x + threadIdx.x; e < NUM_EDGES; e += stride) {
        int r = row[e];
        if (r >= rlo && r < rhi) {
            int pos = atomicAdd(&cursor[r], 1);
            packed[pos] = make_int2(col[e], __float_as_int(val[e]));
        }
    }
}

// ---------------------------------------------------------------------------
// SpMM gather, bf16 propagation buffers: one wave per row, lane = embed dim.
// Per-edge traffic: 128B bf16 x-row (vs 256B fp32) + 8B packed broadcast.
// Wave-cooperative edge fetch + readlane broadcast, 8-deep gather groups.
// MODE 0: y_bf = bf16(acc), out += acc      (layers 1,2)
// MODE 1: out = (out + acc) * 0.25          (layer 3; y not written)
// ---------------------------------------------------------------------------
template <int MODE>
__global__ void spmm_kernel(const int*  __restrict__ row_ptr,
                            const int2* __restrict__ packed,
                            const unsigned short* __restrict__ x,
                            unsigned short*       __restrict__ y,
                            float*                __restrict__ out) {
    int gid  = blockIdx.x * blockDim.x + threadIdx.x;
    int wid  = gid >> 6;           // row
    int lane = gid & 63;           // embed dim
    if (wid >= N_NODES) return;
    int s = row_ptr[wid];
    int e = row_ptr[wid + 1];

    float acc0 = 0.f, acc1 = 0.f, acc2 = 0.f, acc3 = 0.f;
    float acc4 = 0.f, acc5 = 0.f, acc6 = 0.f, acc7 = 0.f;

    for (int base = s; base < e; base += 64) {
        int idx = base + lane;
        int2 pk = make_int2(0, 0);
        if (idx < e) pk = packed[idx];          // one coalesced 512B txn / 64 edges
        int m = e - base; if (m > 64) m = 64;

        int j = 0;
        for (; j + 8 <= m; j += 8) {
            int c0 = __builtin_amdgcn_readlane(pk.x, j + 0);
            int c1 = __builtin_amdgcn_readlane(pk.x, j + 1);
            int c2 = __builtin_amdgcn_readlane(pk.x, j + 2);
            int c3 = __builtin_amdgcn_readlane(pk.x, j + 3);
            int c4 = __builtin_amdgcn_readlane(pk.x, j + 4);
            int c5 = __builtin_amdgcn_readlane(pk.x, j + 5);
            int c6 = __builtin_amdgcn_readlane(pk.x, j + 6);
            int c7 = __builtin_amdgcn_readlane(pk.x, j + 7);
            float x0 = bf2f(x[((long)c0 << 6) + lane]);
            float x1 = bf2f(x[((long)c1 << 6) + lane]);
            float x2 = bf2f(x[((long)c2 << 6) + lane]);
            float x3 = bf2f(x[((long)c3 << 6) + lane]);
            float x4 = bf2f(x[((long)c4 << 6) + lane]);
            float x5 = bf2f(x[((long)c5 << 6) + lane]);
            float x6 = bf2f(x[((long)c6 << 6) + lane]);
            float x7 = bf2f(x[((long)c7 << 6) + lane]);
            float v0 = __int_as_float(__builtin_amdgcn_readlane(pk.y, j + 0));
            float v1 = __int_as_float(__builtin_amdgcn_readlane(pk.y, j + 1));
            float v2 = __int_as_float(__builtin_amdgcn_readlane(pk.y, j + 2));
            float v3 = __int_as_float(__builtin_amdgcn_readlane(pk.y, j + 3));
            float v4 = __int_as_float(__builtin_amdgcn_readlane(pk.y, j + 4));
            float v5 = __int_as_float(__builtin_amdgcn_readlane(pk.y, j + 5));
            float v6 = __int_as_float(__builtin_amdgcn_readlane(pk.y, j + 6));
            float v7 = __int_as_float(__builtin_amdgcn_readlane(pk.y, j + 7));
            acc0 = fmaf(v0, x0, acc0);
            acc1 = fmaf(v1, x1, acc1);
            acc2 = fmaf(v2, x2, acc2);
            acc3 = fmaf(v3, x3, acc3);
            acc4 = fmaf(v4, x4, acc4);
            acc5 = fmaf(v5, x5, acc5);
            acc6 = fmaf(v6, x6, acc6);
            acc7 = fmaf(v7, x7, acc7);
        }
        for (; j < m; ++j) {
            int   c = __builtin_amdgcn_readlane(pk.x, j);
            float v = __int_as_float(__builtin_amdgcn_readlane(pk.y, j));
            acc0 = fmaf(v, bf2f(x[((long)c << 6) + lane]), acc0);
        }
    }
    float acc = ((acc0 + acc1) + (acc2 + acc3)) + ((acc4 + acc5) + (acc6 + acc7));

    long o = ((long)wid << 6) + lane;
    if (MODE == 0) {
        y[o] = f2bf(acc);
        out[o] += acc;
    } else {
        out[o] = (out[o] + acc) * 0.25f;
    }
}

// ------------------- fallback (round-1 atomic path, fp32) -------------------
__global__ void init_fp32_kernel(const float4* __restrict__ ue,
                                 const float4* __restrict__ ie,
                                 float4* __restrict__ cur,
                                 float4* __restrict__ out) {
    int i = blockIdx.x * blockDim.x + threadIdx.x;
    if (i >= N_TOT4) return;
    float4 v = (i < N_USER4) ? ue[i] : ie[i - N_USER4];
    cur[i] = v;
    out[i] = v;
}

__global__ void edge_kernel(const int*   __restrict__ row,
                            const int*   __restrict__ col,
                            const float* __restrict__ val,
                            const float* __restrict__ x,
                            float*       __restrict__ y) {
    long gid = (long)blockIdx.x * blockDim.x + threadIdx.x;
    int e = (int)(gid >> 4);
    if (e >= NUM_EDGES) return;
    int d = ((int)gid & 15) * 4;
    int   r = row[e];
    int   c = col[e];
    float v = val[e];
    const float4 xv = *(const float4*)(x + (long)c * EMBED_DIM + d);
    float* yp = y + (long)r * EMBED_DIM + d;
    atomicAdd(yp + 0, v * xv.x);
    atomicAdd(yp + 1, v * xv.y);
    atomicAdd(yp + 2, v * xv.z);
    atomicAdd(yp + 3, v * xv.w);
}

__global__ void update_kernel(float4* __restrict__ out,
                              const float4* __restrict__ nxt) {
    int i = blockIdx.x * blockDim.x + threadIdx.x;
    if (i >= N_TOT4) return;
    float4 o = out[i], n = nxt[i];
    o.x += n.x; o.y += n.y; o.z += n.z; o.w += n.w;
    out[i] = o;
}

__global__ void final_kernel(float4* __restrict__ out,
                             const float4* __restrict__ nxt) {
    int i = blockIdx.x * blockDim.x + threadIdx.x;
    if (i >= N_TOT4) return;
    float4 o = out[i], n = nxt[i];
    out[i] = make_float4((o.x + n.x) * 0.25f, (o.y + n.y) * 0.25f,
                         (o.z + n.z) * 0.25f, (o.w + n.w) * 0.25f);
}

__global__ void zero_buf_kernel(float4* __restrict__ b) {
    int i = blockIdx.x * blockDim.x + threadIdx.x;
    if (i < N_TOT4) b[i] = make_float4(0.f, 0.f, 0.f, 0.f);
}

extern "C" void kernel_launch(void* const* d_in, const int* in_sizes, int n_in,
                              void* d_out, int out_size, void* d_ws, size_t ws_size,
                              hipStream_t stream) {
    const float* user_emb  = (const float*)d_in[0];
    const float* item_emb  = (const float*)d_in[1];
    const float* edge_vals = (const float*)d_in[2];
    const int*   edge_row  = (const int*)  d_in[3];
    const int*   edge_col  = (const int*)  d_in[4];
    float* out = (float*)d_out;

    const int blk = 256;
    const int grid_nodes = (N_TOT4 + blk - 1) / blk;          // 9375
    const int grid_edges = (NUM_EDGES + blk - 1) / blk;       // 15625
    const int grid_spmm  = (N_NODES * 64 + blk - 1) / blk;    // 37500
    const int grid_scat  = 2048;                              // 8 classes x 256 slices

    const size_t BF     = (size_t)N_NODES * EMBED_DIM * sizeof(unsigned short); // 19.2 MB
    const size_t PACKED = (size_t)NUM_EDGES * sizeof(int2);                     // 32 MB
    const size_t RP     = 600064;                             // (N_NODES+1)*4 padded
    const size_t need   = 2 * BF + PACKED + 2 * RP + 4096;    // ~71.3 MB

    if (ws_size >= need) {
        unsigned short* bfA = (unsigned short*)d_ws;
        unsigned short* bfB = (unsigned short*)((char*)d_ws + BF);
        int2* packed   = (int2*)((char*)d_ws + 2 * BF);
        int*  row_ptr  = (int*) ((char*)d_ws + 2 * BF + PACKED);
        int*  cursor   = (int*) ((char*)d_ws + 2 * BF + PACKED + RP);
        int*  blockSum = (int*) ((char*)d_ws + 2 * BF + PACKED + 2 * RP);

        init_kernel<<<grid_nodes, blk, 0, stream>>>(
            (const float4*)user_emb, (const float4*)item_emb,
            (ushort4*)bfA, (float4*)out);

        // --- build CSR (counts live in `cursor` during hist/scan) ---
        zero_counts<<<NBLK_SCAN, SCAN_BLK, 0, stream>>>(cursor);
        hist_kernel<<<grid_edges, blk, 0, stream>>>(edge_row, cursor);
        scanA<<<NBLK_SCAN, SCAN_BLK, 0, stream>>>(cursor, row_ptr, blockSum);
        scanB<<<1, 1024, 0, stream>>>(blockSum);
        scanC<<<NBLK_SCAN, SCAN_BLK, 0, stream>>>(row_ptr, blockSum, cursor);
        scatter_kernel<<<grid_scat, blk, 0, stream>>>(edge_row, edge_col, edge_vals,
                                                      cursor, packed);

        // --- 3 propagation layers, bf16 gather buffers, fused epilogues ---
        spmm_kernel<0><<<grid_spmm, blk, 0, stream>>>(row_ptr, packed, bfA, bfB, out);
        spmm_kernel<0><<<grid_spmm, blk, 0, stream>>>(row_ptr, packed, bfB, bfA, out);
        spmm_kernel<1><<<grid_spmm, blk, 0, stream>>>(row_ptr, packed, bfA, bfB, out);
    } else {
        // fallback: round-1 atomic scatter path (fp32, needs 76.8 MB)
        const size_t BUF = (size_t)N_NODES * EMBED_DIM * sizeof(float);
        float* bufA = (float*)d_ws;
        float* bufB = (float*)((char*)d_ws + BUF);
        const long edge_threads = (long)NUM_EDGES * 16;
        const int grid_edges16 = (int)((edge_threads + blk - 1) / blk);

        init_fp32_kernel<<<grid_nodes, blk, 0, stream>>>(
            (const float4*)user_emb, (const float4*)item_emb,
            (float4*)bufA, (float4*)out);
        zero_buf_kernel<<<grid_nodes, blk, 0, stream>>>((float4*)bufB);

        edge_kernel<<<grid_edges16, blk, 0, stream>>>(edge_row, edge_col, edge_vals, bufA, bufB);
        update_kernel<<<grid_nodes, blk, 0, stream>>>((float4*)out, (const float4*)bufB);
        zero_buf_kernel<<<grid_nodes, blk, 0, stream>>>((float4*)bufA);

        edge_kernel<<<grid_edges16, blk, 0, stream>>>(edge_row, edge_col, edge_vals, bufB, bufA);
        update_kernel<<<grid_nodes, blk, 0, stream>>>((float4*)out, (const float4*)bufA);
        zero_buf_kernel<<<grid_nodes, blk, 0, stream>>>((float4*)bufB);

        edge_kernel<<<grid_edges16, blk, 0, stream>>>(edge_row, edge_col, edge_vals, bufA, bufB);
        final_kernel<<<grid_nodes, blk, 0, stream>>>((float4*)out, (const float4*)bufB);
    }
}